// Round 1
// baseline (31234.109 us; speedup 1.0000x reference)
//
#include <hip/hip_runtime.h>
#include <hip/hip_cooperative_groups.h>
#include <math.h>

namespace cg = cooperative_groups;

#define H 1024
#define SEQ 256
#define VOUT 32000

__device__ __forceinline__ float sigmoidf_(float x) { return 1.f / (1.f + expf(-x)); }

// ---------------------------------------------------------------------------
// Gather embeddings: blocks 0..255 -> enc_x[t] = enc_emb[input_ids[t]]
//                    blocks 256..511 -> dec_e[t] = dec_emb[dec_in_ids[t]]
// dec_in_ids[0] = START_ID(1), dec_in_ids[t] = target_ids[t-1]
// ---------------------------------------------------------------------------
__global__ __launch_bounds__(256) void gather_kernel(
    const int* __restrict__ input_ids, const int* __restrict__ target_ids,
    const float* __restrict__ enc_emb, const float* __restrict__ dec_emb,
    float* __restrict__ enc_x, float* __restrict__ dec_e)
{
    int b = blockIdx.x, tid = threadIdx.x;
    if (b < SEQ) {
        int tok = input_ids[b];
        const float4* src = (const float4*)(enc_emb + (size_t)tok * H);
        float4* dst = (float4*)(enc_x + (size_t)b * H);
        dst[tid] = src[tid];
    } else {
        int t = b - SEQ;
        int tok = (t == 0) ? 1 : target_ids[t - 1];
        const float4* src = (const float4*)(dec_emb + (size_t)tok * H);
        float4* dst = (float4*)(dec_e + (size_t)t * H);
        dst[tid] = src[tid];
    }
}

__global__ __launch_bounds__(256) void init_kernel(float* __restrict__ hbuf)
{
    int i = blockIdx.x * 256 + threadIdx.x;
    if (i < 2 * H) hbuf[i] = 0.f;
}

// ---------------------------------------------------------------------------
// Generic NT GEMM: C[m,n] = sum_k A[m*lda+offa+k] * B[n*ldb+k] (+ bias[n])
// Tile 64x64, K-step 16. LDS stored k-major so the inner loop does float4 reads.
// Requires M%64==0, N%64==0, K%16==0. grid = (N/64, M/64), block = 256.
// ---------------------------------------------------------------------------
__global__ __launch_bounds__(256) void gemm_nt_kernel(
    const float* __restrict__ A, const float* __restrict__ B,
    const float* __restrict__ bias, float* __restrict__ C,
    int Kdim, int lda, int offa, int ldb, int ldc)
{
    __shared__ float As[16][68];
    __shared__ float Bs[16][68];
    const int tid = threadIdx.x;
    const int m0 = blockIdx.y * 64;
    const int n0 = blockIdx.x * 64;
    const int tr = (tid >> 4) << 2;   // row offset in tile: 0..60
    const int tc = (tid & 15) << 2;   // col offset in tile: 0..60
    const int lrow = tid >> 2;        // 0..63 (tile row for loads)
    const int lk = (tid & 3) << 2;    // 0,4,8,12 (k offset for loads)
    const float* Ab = A + (size_t)m0 * lda + offa;
    const float* Bb = B + (size_t)n0 * ldb;
    float acc[4][4] = {{0.f,0.f,0.f,0.f},{0.f,0.f,0.f,0.f},{0.f,0.f,0.f,0.f},{0.f,0.f,0.f,0.f}};

    for (int k0 = 0; k0 < Kdim; k0 += 16) {
        float4 av = *(const float4*)(Ab + (size_t)lrow * lda + (k0 + lk));
        float4 bv = *(const float4*)(Bb + (size_t)lrow * ldb + (k0 + lk));
        As[lk + 0][lrow] = av.x; As[lk + 1][lrow] = av.y;
        As[lk + 2][lrow] = av.z; As[lk + 3][lrow] = av.w;
        Bs[lk + 0][lrow] = bv.x; Bs[lk + 1][lrow] = bv.y;
        Bs[lk + 2][lrow] = bv.z; Bs[lk + 3][lrow] = bv.w;
        __syncthreads();
#pragma unroll
        for (int k = 0; k < 16; ++k) {
            float4 a = *(const float4*)(&As[k][tr]);
            float4 b = *(const float4*)(&Bs[k][tc]);
            acc[0][0] = fmaf(a.x, b.x, acc[0][0]);
            acc[0][1] = fmaf(a.x, b.y, acc[0][1]);
            acc[0][2] = fmaf(a.x, b.z, acc[0][2]);
            acc[0][3] = fmaf(a.x, b.w, acc[0][3]);
            acc[1][0] = fmaf(a.y, b.x, acc[1][0]);
            acc[1][1] = fmaf(a.y, b.y, acc[1][1]);
            acc[1][2] = fmaf(a.y, b.z, acc[1][2]);
            acc[1][3] = fmaf(a.y, b.w, acc[1][3]);
            acc[2][0] = fmaf(a.z, b.x, acc[2][0]);
            acc[2][1] = fmaf(a.z, b.y, acc[2][1]);
            acc[2][2] = fmaf(a.z, b.z, acc[2][2]);
            acc[2][3] = fmaf(a.z, b.w, acc[2][3]);
            acc[3][0] = fmaf(a.w, b.x, acc[3][0]);
            acc[3][1] = fmaf(a.w, b.y, acc[3][1]);
            acc[3][2] = fmaf(a.w, b.z, acc[3][2]);
            acc[3][3] = fmaf(a.w, b.w, acc[3][3]);
        }
        __syncthreads();
    }
#pragma unroll
    for (int i = 0; i < 4; ++i) {
#pragma unroll
        for (int j = 0; j < 4; ++j) {
            float v = acc[i][j];
            if (bias) v += bias[n0 + tc + j];
            C[(size_t)(m0 + tr + i) * ldc + (n0 + tc + j)] = v;
        }
    }
}

// ---------------------------------------------------------------------------
// Encoder recurrence (cooperative, 256 blocks x 256 threads).
// Block b, wave w owns hidden unit u = b*4+w. Per step: 3 dots of length H
// over h (from LDS), gates, write h2. One grid sync per step.
// gi_all[t, 3H] already contains enc_Wi@x + enc_bi.
// ---------------------------------------------------------------------------
__global__ __launch_bounds__(256) void enc_rnn_kernel(
    const float* __restrict__ Wh, const float* __restrict__ bh,
    const float* __restrict__ gi_all,
    float* __restrict__ hbuf, float* __restrict__ encH)
{
    cg::grid_group grid = cg::this_grid();
    __shared__ float h_s[H];
    const int tid = threadIdx.x;
    const int wave = tid >> 6, lane = tid & 63;
    const int u = blockIdx.x * 4 + wave;
    const float* wr = Wh + (size_t)u * H;
    const float* wz = Wh + (size_t)(u + H) * H;
    const float* wn = Wh + (size_t)(u + 2 * H) * H;

    for (int t = 0; t < SEQ; ++t) {
        const float* h = hbuf + (t & 1) * H;
        float* hnext = hbuf + ((t + 1) & 1) * H;
        for (int i = tid; i < H; i += 256) h_s[i] = h[i];
        __syncthreads();

        float dr = 0.f, dz = 0.f, dn = 0.f;
#pragma unroll 4
        for (int k = lane; k < H; k += 64) {
            float hv = h_s[k];
            dr = fmaf(wr[k], hv, dr);
            dz = fmaf(wz[k], hv, dz);
            dn = fmaf(wn[k], hv, dn);
        }
#pragma unroll
        for (int off = 32; off > 0; off >>= 1) {
            dr += __shfl_down(dr, off);
            dz += __shfl_down(dz, off);
            dn += __shfl_down(dn, off);
        }
        if (lane == 0) {
            float gir = gi_all[t * 3 * H + u];
            float giz = gi_all[t * 3 * H + H + u];
            float gin = gi_all[t * 3 * H + 2 * H + u];
            float r = sigmoidf_(gir + dr + bh[u]);
            float z = sigmoidf_(giz + dz + bh[H + u]);
            float n = tanhf(gin + r * (dn + bh[2 * H + u]));
            float h2 = (1.f - z) * n + z * h_s[u];
            hnext[u] = h2;
            encH[(size_t)t * H + u] = h2;
        }
        grid.sync();
    }
}

// ---------------------------------------------------------------------------
// Decoder recurrence (cooperative, 256 blocks x 256 threads), 3 syncs/step.
// Stage1: block b computes score s[b] = attn_e[t,b] + attn_W[b,H:]@h
// Stage2: softmax (block-redundant over 256 scores) + c[u] = relu(comb_pre +
//         (a@M[u,:])/sum)  -- M = comb_W[:,H:] @ enc_outs^T precomputed.
// Stage3: GRU: 6 dots per unit (Wi rows over c, Wh rows over h), gates.
// ---------------------------------------------------------------------------
__global__ __launch_bounds__(256) void dec_rnn_kernel(
    const float* __restrict__ attn_W, const float* __restrict__ attn_e,
    const float* __restrict__ M, const float* __restrict__ comb_pre,
    const float* __restrict__ Wi, const float* __restrict__ Wh,
    const float* __restrict__ bi, const float* __restrict__ bh,
    float* __restrict__ hbuf, float* __restrict__ s_g,
    float* __restrict__ c_g, float* __restrict__ hs_dec)
{
    cg::grid_group grid = cg::this_grid();
    __shared__ float h_s[H];
    __shared__ float c_s[H];
    __shared__ float a_s[SEQ];
    __shared__ float red[256];
    const int b = blockIdx.x, tid = threadIdx.x;
    const int wave = tid >> 6, lane = tid & 63;
    const int u = b * 4 + wave;
    const float* arow = attn_W + (size_t)b * (2 * H) + H;
    const float* Mrow = M + (size_t)u * SEQ;
    const float* wir = Wi + (size_t)u * H;
    const float* wiz = Wi + (size_t)(u + H) * H;
    const float* win = Wi + (size_t)(u + 2 * H) * H;
    const float* whr = Wh + (size_t)u * H;
    const float* whz = Wh + (size_t)(u + H) * H;
    const float* whn = Wh + (size_t)(u + 2 * H) * H;

    for (int t = 0; t < SEQ; ++t) {
        const float* h = hbuf + (t & 1) * H;
        float* hnext = hbuf + ((t + 1) & 1) * H;
        for (int i = tid; i < H; i += 256) h_s[i] = h[i];
        __syncthreads();

        // ---- stage 1: attention score for l = b ----
        float p = 0.f;
        for (int k = tid; k < H; k += 256) p = fmaf(arow[k], h_s[k], p);
        red[tid] = p;
        __syncthreads();
        for (int off = 128; off > 0; off >>= 1) {
            if (tid < off) red[tid] += red[tid + off];
            __syncthreads();
        }
        if (tid == 0) s_g[b] = red[0] + attn_e[t * SEQ + b];
        grid.sync();

        // ---- stage 2: softmax + combined input c ----
        float sv = s_g[tid];
        red[tid] = sv;
        __syncthreads();
        for (int off = 128; off > 0; off >>= 1) {
            if (tid < off) red[tid] = fmaxf(red[tid], red[tid + off]);
            __syncthreads();
        }
        float mx = red[0];
        __syncthreads();
        float ev = expf(sv - mx);
        a_s[tid] = ev;
        red[tid] = ev;
        __syncthreads();
        for (int off = 128; off > 0; off >>= 1) {
            if (tid < off) red[tid] += red[tid + off];
            __syncthreads();
        }
        float inv = 1.f / red[0];
        float pc = 0.f;
#pragma unroll 4
        for (int k = lane; k < SEQ; k += 64) pc = fmaf(a_s[k], Mrow[k], pc);
#pragma unroll
        for (int off = 32; off > 0; off >>= 1) pc += __shfl_down(pc, off);
        if (lane == 0) c_g[u] = fmaxf(0.f, comb_pre[t * H + u] + pc * inv);
        grid.sync();

        // ---- stage 3: GRU cell ----
        for (int i = tid; i < H; i += 256) c_s[i] = c_g[i];
        __syncthreads();
        float dir = 0.f, diz = 0.f, din = 0.f, dhr = 0.f, dhz = 0.f, dhn = 0.f;
#pragma unroll 2
        for (int k = lane; k < H; k += 64) {
            float cv = c_s[k], hv = h_s[k];
            dir = fmaf(wir[k], cv, dir);
            diz = fmaf(wiz[k], cv, diz);
            din = fmaf(win[k], cv, din);
            dhr = fmaf(whr[k], hv, dhr);
            dhz = fmaf(whz[k], hv, dhz);
            dhn = fmaf(whn[k], hv, dhn);
        }
#pragma unroll
        for (int off = 32; off > 0; off >>= 1) {
            dir += __shfl_down(dir, off); diz += __shfl_down(diz, off);
            din += __shfl_down(din, off); dhr += __shfl_down(dhr, off);
            dhz += __shfl_down(dhz, off); dhn += __shfl_down(dhn, off);
        }
        if (lane == 0) {
            float r = sigmoidf_(dir + bi[u] + dhr + bh[u]);
            float z = sigmoidf_(diz + bi[H + u] + dhz + bh[H + u]);
            float n = tanhf(din + bi[2 * H + u] + r * (dhn + bh[2 * H + u]));
            float h2 = (1.f - z) * n + z * h_s[u];
            hnext[u] = h2;
            hs_dec[(size_t)t * H + u] = h2;
        }
        grid.sync();
    }
}

// ---------------------------------------------------------------------------
// NLL: block t scans logits[t, 0:32000]: logsumexp + gather target.
// ---------------------------------------------------------------------------
__global__ __launch_bounds__(256) void nll_kernel(
    const float* __restrict__ logits, const int* __restrict__ target_ids,
    float* __restrict__ nll)
{
    const int t = blockIdx.x, tid = threadIdx.x;
    __shared__ float red[256];
    const float* row = logits + (size_t)t * VOUT;
    float mx = -1e30f;
    for (int i = tid; i < VOUT; i += 256) mx = fmaxf(mx, row[i]);
    red[tid] = mx;
    __syncthreads();
    for (int off = 128; off > 0; off >>= 1) {
        if (tid < off) red[tid] = fmaxf(red[tid], red[tid + off]);
        __syncthreads();
    }
    mx = red[0];
    __syncthreads();
    float s = 0.f;
    for (int i = tid; i < VOUT; i += 256) s += expf(row[i] - mx);
    red[tid] = s;
    __syncthreads();
    for (int off = 128; off > 0; off >>= 1) {
        if (tid < off) red[tid] += red[tid + off];
        __syncthreads();
    }
    if (tid == 0) {
        float lse = mx + logf(red[0]);
        nll[t] = lse - row[target_ids[t]];
    }
}

__global__ __launch_bounds__(256) void sum_kernel(
    const float* __restrict__ nll, float* __restrict__ out)
{
    __shared__ float red[256];
    int tid = threadIdx.x;
    red[tid] = nll[tid];
    __syncthreads();
    for (int off = 128; off > 0; off >>= 1) {
        if (tid < off) red[tid] += red[tid + off];
        __syncthreads();
    }
    if (tid == 0) out[0] = red[0];
}

// ---------------------------------------------------------------------------
extern "C" void kernel_launch(void* const* d_in, const int* in_sizes, int n_in,
                              void* d_out, int out_size, void* d_ws, size_t ws_size,
                              hipStream_t stream)
{
    const int*   input_ids  = (const int*)d_in[0];
    const int*   target_ids = (const int*)d_in[1];
    const float* enc_emb = (const float*)d_in[2];
    const float* enc_Wi  = (const float*)d_in[3];
    const float* enc_Wh  = (const float*)d_in[4];
    const float* enc_bi  = (const float*)d_in[5];
    const float* enc_bh  = (const float*)d_in[6];
    const float* dec_emb = (const float*)d_in[7];
    const float* dec_Wi  = (const float*)d_in[8];
    const float* dec_Wh  = (const float*)d_in[9];
    const float* dec_bi  = (const float*)d_in[10];
    const float* dec_bh  = (const float*)d_in[11];
    const float* attn_W  = (const float*)d_in[12];
    const float* attn_b  = (const float*)d_in[13];
    const float* comb_W  = (const float*)d_in[14];
    const float* comb_b  = (const float*)d_in[15];
    const float* out_W   = (const float*)d_in[16];
    const float* out_b   = (const float*)d_in[17];
    float* out = (float*)d_out;

    float* ws = (float*)d_ws;
    float* enc_x    = ws; ws += SEQ * H;          // 256x1024
    float* dec_e    = ws; ws += SEQ * H;          // 256x1024
    float* enc_gi   = ws; ws += SEQ * 3 * H;      // 256x3072
    float* attn_e   = ws; ws += SEQ * SEQ;        // 256x256
    float* comb_pre = ws; ws += SEQ * H;          // 256x1024
    float* Mmat     = ws; ws += H * SEQ;          // 1024x256
    float* encH     = ws; ws += SEQ * H;          // 256x1024
    float* hs_dec   = ws; ws += SEQ * H;          // 256x1024
    float* hbuf     = ws; ws += 2 * H;            // double-buffered h
    float* s_g      = ws; ws += SEQ;
    float* c_g      = ws; ws += H;
    float* nll      = ws; ws += SEQ;
    ws += (256 - ((ws - (float*)d_ws) & 255)) & 255;  // align
    float* logits   = ws; ws += (size_t)SEQ * VOUT;   // 256x32000 (32.8 MB)

    // phase 0: gathers + zero h
    hipLaunchKernelGGL(gather_kernel, dim3(512), dim3(256), 0, stream,
                       input_ids, target_ids, enc_emb, dec_emb, enc_x, dec_e);
    hipLaunchKernelGGL(init_kernel, dim3(8), dim3(256), 0, stream, hbuf);

    // phase 1: batched pre-GEMMs
    // enc_gi[t,r] = enc_x @ enc_Wi^T + enc_bi
    hipLaunchKernelGGL(gemm_nt_kernel, dim3(3 * H / 64, SEQ / 64), dim3(256), 0, stream,
                       enc_x, enc_Wi, enc_bi, enc_gi, H, H, 0, H, 3 * H);
    // attn_e[t,l] = dec_e @ attn_W[:, :H]^T + attn_b
    hipLaunchKernelGGL(gemm_nt_kernel, dim3(SEQ / 64, SEQ / 64), dim3(256), 0, stream,
                       dec_e, attn_W, attn_b, attn_e, H, H, 0, 2 * H, SEQ);
    // comb_pre[t,j] = dec_e @ comb_W[:, :H]^T + comb_b
    hipLaunchKernelGGL(gemm_nt_kernel, dim3(H / 64, SEQ / 64), dim3(256), 0, stream,
                       dec_e, comb_W, comb_b, comb_pre, H, H, 0, 2 * H, H);

    // phase 2: encoder recurrence (cooperative)
    {
        void* args[] = {(void*)&enc_Wh, (void*)&enc_bh, (void*)&enc_gi,
                        (void*)&hbuf, (void*)&encH};
        hipLaunchCooperativeKernel((void*)enc_rnn_kernel, dim3(256), dim3(256),
                                   args, 0, stream);
    }

    // phase 2.5: M[j,t'] = comb_W[:, H:] @ encH^T
    hipLaunchKernelGGL(gemm_nt_kernel, dim3(SEQ / 64, H / 64), dim3(256), 0, stream,
                       comb_W, encH, (const float*)nullptr, Mmat, H, 2 * H, H, H, SEQ);

    // phase 3: decoder recurrence (cooperative)
    {
        void* args[] = {(void*)&attn_W, (void*)&attn_e, (void*)&Mmat, (void*)&comb_pre,
                        (void*)&dec_Wi, (void*)&dec_Wh, (void*)&dec_bi, (void*)&dec_bh,
                        (void*)&hbuf, (void*)&s_g, (void*)&c_g, (void*)&hs_dec};
        hipLaunchCooperativeKernel((void*)dec_rnn_kernel, dim3(256), dim3(256),
                                   args, 0, stream);
    }

    // phase 4: logits = hs_dec @ out_W^T + out_b  (the 78%-of-FLOPs GEMM)
    hipLaunchKernelGGL(gemm_nt_kernel, dim3(VOUT / 64, SEQ / 64), dim3(256), 0, stream,
                       hs_dec, out_W, out_b, logits, H, H, 0, H, VOUT);

    // phase 5: per-step NLL + total
    hipLaunchKernelGGL(nll_kernel, dim3(SEQ), dim3(256), 0, stream,
                       logits, target_ids, nll);
    hipLaunchKernelGGL(sum_kernel, dim3(1), dim3(256), 0, stream, nll, out);
}

// Round 2
// 5718.050 us; speedup vs baseline: 5.4624x; 5.4624x over previous
//
#include <hip/hip_runtime.h>
#include <math.h>

#define H 1024
#define SEQ 256
#define VOUT 32000

__device__ __forceinline__ float sigmoidf_(float x) { return 1.f / (1.f + expf(-x)); }

// ---------------------------------------------------------------------------
// Device-coherent (cross-XCD) access helpers: relaxed agent-scope atomics.
// These bypass the non-coherent per-XCD caches WITHOUT emitting any cache
// invalidate/writeback, so read-only weights stay warm in L1/L2.
// ---------------------------------------------------------------------------
__device__ __forceinline__ float cload(const float* p) {
    return __hip_atomic_load(p, __ATOMIC_RELAXED, __HIP_MEMORY_SCOPE_AGENT);
}
__device__ __forceinline__ void cstore(float* p, float v) {
    __hip_atomic_store(p, v, __ATOMIC_RELAXED, __HIP_MEMORY_SCOPE_AGENT);
}

// ---------------------------------------------------------------------------
// Fast grid barrier: 2-level monotonic arrival tree + generation spin.
// bar layout (ints): leaf i at [i*16] (16 leaves, 64B apart), root at [320],
// gen at [384]. All zeroed by init_kernel each launch.
// Precondition: called by all 256 blocks with the same monotonically
// increasing `target` (1,2,3,...). __syncthreads() before arrival guarantees
// every wave's stores have completed (compiler emits vmcnt(0) before
// s_barrier), so coherent readers after the barrier see them.
// ---------------------------------------------------------------------------
__device__ __forceinline__ void gbar(int* bar, int target) {
    __syncthreads();
    if (threadIdx.x == 0) {
        int* leaf = bar + ((blockIdx.x & 15) << 4);
        int a = __hip_atomic_fetch_add(leaf, 1, __ATOMIC_RELAXED, __HIP_MEMORY_SCOPE_AGENT);
        if (a == 16 * target - 1) {
            int r = __hip_atomic_fetch_add(bar + 320, 1, __ATOMIC_RELAXED, __HIP_MEMORY_SCOPE_AGENT);
            if (r == 16 * target - 1) {
                __hip_atomic_store(bar + 384, target, __ATOMIC_RELAXED, __HIP_MEMORY_SCOPE_AGENT);
            }
        }
        while (__hip_atomic_load(bar + 384, __ATOMIC_RELAXED, __HIP_MEMORY_SCOPE_AGENT) < target) {
            __builtin_amdgcn_s_sleep(2);
        }
    }
    __syncthreads();
}

// ---------------------------------------------------------------------------
__global__ __launch_bounds__(256) void gather_kernel(
    const int* __restrict__ input_ids, const int* __restrict__ target_ids,
    const float* __restrict__ enc_emb, const float* __restrict__ dec_emb,
    float* __restrict__ enc_x, float* __restrict__ dec_e)
{
    int b = blockIdx.x, tid = threadIdx.x;
    if (b < SEQ) {
        int tok = input_ids[b];
        const float4* src = (const float4*)(enc_emb + (size_t)tok * H);
        float4* dst = (float4*)(enc_x + (size_t)b * H);
        dst[tid] = src[tid];
    } else {
        int t = b - SEQ;
        int tok = (t == 0) ? 1 : target_ids[t - 1];
        const float4* src = (const float4*)(dec_emb + (size_t)tok * H);
        float4* dst = (float4*)(dec_e + (size_t)t * H);
        dst[tid] = src[tid];
    }
}

// zero hbuf (2H floats) + barrier state (1024 ints) — re-run every launch
// because the harness poisons d_ws with 0xAA.
__global__ __launch_bounds__(256) void init_kernel(float* __restrict__ hbuf,
                                                   int* __restrict__ bar)
{
    int i = blockIdx.x * 256 + threadIdx.x;
    if (i < 2 * H) hbuf[i] = 0.f;
    if (i < 1024) bar[i] = 0;
}

// ---------------------------------------------------------------------------
// Generic NT GEMM: C[m,n] = sum_k A[m*lda+offa+k] * B[n*ldb+k] (+ bias[n])
// ---------------------------------------------------------------------------
__global__ __launch_bounds__(256) void gemm_nt_kernel(
    const float* __restrict__ A, const float* __restrict__ B,
    const float* __restrict__ bias, float* __restrict__ C,
    int Kdim, int lda, int offa, int ldb, int ldc)
{
    __shared__ float As[16][68];
    __shared__ float Bs[16][68];
    const int tid = threadIdx.x;
    const int m0 = blockIdx.y * 64;
    const int n0 = blockIdx.x * 64;
    const int tr = (tid >> 4) << 2;
    const int tc = (tid & 15) << 2;
    const int lrow = tid >> 2;
    const int lk = (tid & 3) << 2;
    const float* Ab = A + (size_t)m0 * lda + offa;
    const float* Bb = B + (size_t)n0 * ldb;
    float acc[4][4] = {{0.f,0.f,0.f,0.f},{0.f,0.f,0.f,0.f},{0.f,0.f,0.f,0.f},{0.f,0.f,0.f,0.f}};

    for (int k0 = 0; k0 < Kdim; k0 += 16) {
        float4 av = *(const float4*)(Ab + (size_t)lrow * lda + (k0 + lk));
        float4 bv = *(const float4*)(Bb + (size_t)lrow * ldb + (k0 + lk));
        As[lk + 0][lrow] = av.x; As[lk + 1][lrow] = av.y;
        As[lk + 2][lrow] = av.z; As[lk + 3][lrow] = av.w;
        Bs[lk + 0][lrow] = bv.x; Bs[lk + 1][lrow] = bv.y;
        Bs[lk + 2][lrow] = bv.z; Bs[lk + 3][lrow] = bv.w;
        __syncthreads();
#pragma unroll
        for (int k = 0; k < 16; ++k) {
            float4 a = *(const float4*)(&As[k][tr]);
            float4 b = *(const float4*)(&Bs[k][tc]);
            acc[0][0] = fmaf(a.x, b.x, acc[0][0]);
            acc[0][1] = fmaf(a.x, b.y, acc[0][1]);
            acc[0][2] = fmaf(a.x, b.z, acc[0][2]);
            acc[0][3] = fmaf(a.x, b.w, acc[0][3]);
            acc[1][0] = fmaf(a.y, b.x, acc[1][0]);
            acc[1][1] = fmaf(a.y, b.y, acc[1][1]);
            acc[1][2] = fmaf(a.y, b.z, acc[1][2]);
            acc[1][3] = fmaf(a.y, b.w, acc[1][3]);
            acc[2][0] = fmaf(a.z, b.x, acc[2][0]);
            acc[2][1] = fmaf(a.z, b.y, acc[2][1]);
            acc[2][2] = fmaf(a.z, b.z, acc[2][2]);
            acc[2][3] = fmaf(a.z, b.w, acc[2][3]);
            acc[3][0] = fmaf(a.w, b.x, acc[3][0]);
            acc[3][1] = fmaf(a.w, b.y, acc[3][1]);
            acc[3][2] = fmaf(a.w, b.z, acc[3][2]);
            acc[3][3] = fmaf(a.w, b.w, acc[3][3]);
        }
        __syncthreads();
    }
#pragma unroll
    for (int i = 0; i < 4; ++i) {
#pragma unroll
        for (int j = 0; j < 4; ++j) {
            float v = acc[i][j];
            if (bias) v += bias[n0 + tc + j];
            C[(size_t)(m0 + tr + i) * ldc + (n0 + tc + j)] = v;
        }
    }
}

// ---------------------------------------------------------------------------
// Encoder recurrence: 256 blocks x 256 threads, wave w of block b owns unit
// u = b*4+w. One custom barrier per step.
// ---------------------------------------------------------------------------
__global__ __launch_bounds__(256) void enc_rnn_kernel(
    const float* __restrict__ Wh, const float* __restrict__ bh,
    const float* __restrict__ gi_all,
    float* __restrict__ hbuf, float* __restrict__ encH, int* __restrict__ bar)
{
    __shared__ float h_s[H];
    const int tid = threadIdx.x;
    const int wave = tid >> 6, lane = tid & 63;
    const int u = blockIdx.x * 4 + wave;
    const float* wr = Wh + (size_t)u * H;
    const float* wz = Wh + (size_t)(u + H) * H;
    const float* wn = Wh + (size_t)(u + 2 * H) * H;

    for (int t = 0; t < SEQ; ++t) {
        const float* h = hbuf + (t & 1) * H;
        float* hnext = hbuf + ((t + 1) & 1) * H;
        for (int i = tid; i < H; i += 256) h_s[i] = cload(h + i);
        __syncthreads();

        float dr = 0.f, dz = 0.f, dn = 0.f;
#pragma unroll 4
        for (int k = lane; k < H; k += 64) {
            float hv = h_s[k];
            dr = fmaf(wr[k], hv, dr);
            dz = fmaf(wz[k], hv, dz);
            dn = fmaf(wn[k], hv, dn);
        }
#pragma unroll
        for (int off = 32; off > 0; off >>= 1) {
            dr += __shfl_down(dr, off);
            dz += __shfl_down(dz, off);
            dn += __shfl_down(dn, off);
        }
        if (lane == 0) {
            float gir = gi_all[t * 3 * H + u];
            float giz = gi_all[t * 3 * H + H + u];
            float gin = gi_all[t * 3 * H + 2 * H + u];
            float r = sigmoidf_(gir + dr + bh[u]);
            float z = sigmoidf_(giz + dz + bh[H + u]);
            float n = tanhf(gin + r * (dn + bh[2 * H + u]));
            float h2 = (1.f - z) * n + z * h_s[u];
            cstore(hnext + u, h2);
            encH[(size_t)t * H + u] = h2;
        }
        gbar(bar, t + 1);
    }
}

// ---------------------------------------------------------------------------
// Decoder recurrence: 3 custom barriers per step. Wave shuffles for all
// reductions; cross-block data via coherent atomics.
// ---------------------------------------------------------------------------
__global__ __launch_bounds__(256) void dec_rnn_kernel(
    const float* __restrict__ attn_W, const float* __restrict__ attn_e,
    const float* __restrict__ M, const float* __restrict__ comb_pre,
    const float* __restrict__ Wi, const float* __restrict__ Wh,
    const float* __restrict__ bi, const float* __restrict__ bh,
    float* __restrict__ hbuf, float* __restrict__ s_g,
    float* __restrict__ c_g, float* __restrict__ hs_dec, int* __restrict__ bar)
{
    __shared__ float h_s[H];
    __shared__ float c_s[H];
    __shared__ float a_s[SEQ];
    __shared__ float red4[4];
    const int b = blockIdx.x, tid = threadIdx.x;
    const int wave = tid >> 6, lane = tid & 63;
    const int u = b * 4 + wave;
    const float* arow = attn_W + (size_t)b * (2 * H) + H;
    const float* Mrow = M + (size_t)u * SEQ;
    const float* wir = Wi + (size_t)u * H;
    const float* wiz = Wi + (size_t)(u + H) * H;
    const float* win = Wi + (size_t)(u + 2 * H) * H;
    const float* whr = Wh + (size_t)u * H;
    const float* whz = Wh + (size_t)(u + H) * H;
    const float* whn = Wh + (size_t)(u + 2 * H) * H;

    for (int t = 0; t < SEQ; ++t) {
        const float* h = hbuf + (t & 1) * H;
        float* hnext = hbuf + ((t + 1) & 1) * H;
        for (int i = tid; i < H; i += 256) h_s[i] = cload(h + i);
        __syncthreads();

        // ---- stage 1: score[b] = attn_e[t,b] + attn_W[b,H:] @ h ----
        float p = 0.f;
#pragma unroll 4
        for (int k = tid; k < H; k += 256) p = fmaf(arow[k], h_s[k], p);
#pragma unroll
        for (int off = 32; off > 0; off >>= 1) p += __shfl_down(p, off);
        if (lane == 0) red4[wave] = p;
        __syncthreads();
        if (tid == 0)
            cstore(s_g + b, red4[0] + red4[1] + red4[2] + red4[3] + attn_e[t * SEQ + b]);
        gbar(bar, 3 * t + 1);

        // ---- stage 2: softmax (block-redundant) + c[u] ----
        float sv = cload(s_g + tid);
        float m = sv;
#pragma unroll
        for (int off = 32; off > 0; off >>= 1) m = fmaxf(m, __shfl_down(m, off));
        if (lane == 0) red4[wave] = m;
        __syncthreads();
        float mx = fmaxf(fmaxf(red4[0], red4[1]), fmaxf(red4[2], red4[3]));
        float ev = expf(sv - mx);
        a_s[tid] = ev;
        float ssum = ev;
#pragma unroll
        for (int off = 32; off > 0; off >>= 1) ssum += __shfl_down(ssum, off);
        __syncthreads();                 // readers of red4 (mx) done; a_s visible
        if (lane == 0) red4[wave] = ssum;
        __syncthreads();
        float inv = 1.f / (red4[0] + red4[1] + red4[2] + red4[3]);
        float pc = 0.f;
#pragma unroll 4
        for (int k = lane; k < SEQ; k += 64) pc = fmaf(a_s[k], Mrow[k], pc);
#pragma unroll
        for (int off = 32; off > 0; off >>= 1) pc += __shfl_down(pc, off);
        if (lane == 0)
            cstore(c_g + u, fmaxf(0.f, comb_pre[t * H + u] + pc * inv));
        gbar(bar, 3 * t + 2);

        // ---- stage 3: GRU cell ----
        for (int i = tid; i < H; i += 256) c_s[i] = cload(c_g + i);
        __syncthreads();
        float dir = 0.f, diz = 0.f, din = 0.f, dhr = 0.f, dhz = 0.f, dhn = 0.f;
#pragma unroll 2
        for (int k = lane; k < H; k += 64) {
            float cv = c_s[k], hv = h_s[k];
            dir = fmaf(wir[k], cv, dir);
            diz = fmaf(wiz[k], cv, diz);
            din = fmaf(win[k], cv, din);
            dhr = fmaf(whr[k], hv, dhr);
            dhz = fmaf(whz[k], hv, dhz);
            dhn = fmaf(whn[k], hv, dhn);
        }
#pragma unroll
        for (int off = 32; off > 0; off >>= 1) {
            dir += __shfl_down(dir, off); diz += __shfl_down(diz, off);
            din += __shfl_down(din, off); dhr += __shfl_down(dhr, off);
            dhz += __shfl_down(dhz, off); dhn += __shfl_down(dhn, off);
        }
        if (lane == 0) {
            float r = sigmoidf_(dir + bi[u] + dhr + bh[u]);
            float z = sigmoidf_(diz + bi[H + u] + dhz + bh[H + u]);
            float n = tanhf(din + bi[2 * H + u] + r * (dhn + bh[2 * H + u]));
            float h2 = (1.f - z) * n + z * h_s[u];
            cstore(hnext + u, h2);
            hs_dec[(size_t)t * H + u] = h2;
        }
        gbar(bar, 3 * t + 3);
    }
}

// ---------------------------------------------------------------------------
__global__ __launch_bounds__(256) void nll_kernel(
    const float* __restrict__ logits, const int* __restrict__ target_ids,
    float* __restrict__ nll)
{
    const int t = blockIdx.x, tid = threadIdx.x;
    __shared__ float red[256];
    const float* row = logits + (size_t)t * VOUT;
    float mx = -1e30f;
    for (int i = tid; i < VOUT; i += 256) mx = fmaxf(mx, row[i]);
    red[tid] = mx;
    __syncthreads();
    for (int off = 128; off > 0; off >>= 1) {
        if (tid < off) red[tid] = fmaxf(red[tid], red[tid + off]);
        __syncthreads();
    }
    mx = red[0];
    __syncthreads();
    float s = 0.f;
    for (int i = tid; i < VOUT; i += 256) s += expf(row[i] - mx);
    red[tid] = s;
    __syncthreads();
    for (int off = 128; off > 0; off >>= 1) {
        if (tid < off) red[tid] += red[tid + off];
        __syncthreads();
    }
    if (tid == 0) {
        float lse = mx + logf(red[0]);
        nll[t] = lse - row[target_ids[t]];
    }
}

__global__ __launch_bounds__(256) void sum_kernel(
    const float* __restrict__ nll, float* __restrict__ out)
{
    __shared__ float red[256];
    int tid = threadIdx.x;
    red[tid] = nll[tid];
    __syncthreads();
    for (int off = 128; off > 0; off >>= 1) {
        if (tid < off) red[tid] += red[tid + off];
        __syncthreads();
    }
    if (tid == 0) out[0] = red[0];
}

// ---------------------------------------------------------------------------
extern "C" void kernel_launch(void* const* d_in, const int* in_sizes, int n_in,
                              void* d_out, int out_size, void* d_ws, size_t ws_size,
                              hipStream_t stream)
{
    const int*   input_ids  = (const int*)d_in[0];
    const int*   target_ids = (const int*)d_in[1];
    const float* enc_emb = (const float*)d_in[2];
    const float* enc_Wi  = (const float*)d_in[3];
    const float* enc_Wh  = (const float*)d_in[4];
    const float* enc_bi  = (const float*)d_in[5];
    const float* enc_bh  = (const float*)d_in[6];
    const float* dec_emb = (const float*)d_in[7];
    const float* dec_Wi  = (const float*)d_in[8];
    const float* dec_Wh  = (const float*)d_in[9];
    const float* dec_bi  = (const float*)d_in[10];
    const float* dec_bh  = (const float*)d_in[11];
    const float* attn_W  = (const float*)d_in[12];
    const float* attn_b  = (const float*)d_in[13];
    const float* comb_W  = (const float*)d_in[14];
    const float* comb_b  = (const float*)d_in[15];
    const float* out_W   = (const float*)d_in[16];
    const float* out_b   = (const float*)d_in[17];
    float* out = (float*)d_out;

    float* ws = (float*)d_ws;
    float* enc_x    = ws; ws += SEQ * H;
    float* dec_e    = ws; ws += SEQ * H;
    float* enc_gi   = ws; ws += SEQ * 3 * H;
    float* attn_e   = ws; ws += SEQ * SEQ;
    float* comb_pre = ws; ws += SEQ * H;
    float* Mmat     = ws; ws += H * SEQ;
    float* encH     = ws; ws += SEQ * H;
    float* hs_dec   = ws; ws += SEQ * H;
    float* hbuf     = ws; ws += 2 * H;
    float* s_g      = ws; ws += SEQ;
    float* c_g      = ws; ws += H;
    float* nll      = ws; ws += SEQ;
    int*   bar_all  = (int*)ws; ws += 1024;       // enc bar at +0, dec bar at +512
    ws += (256 - ((ws - (float*)d_ws) & 255)) & 255;
    float* logits   = ws; ws += (size_t)SEQ * VOUT;

    int* bar_enc = bar_all;
    int* bar_dec = bar_all + 512;

    // phase 0: gathers + zero h/barriers
    hipLaunchKernelGGL(gather_kernel, dim3(512), dim3(256), 0, stream,
                       input_ids, target_ids, enc_emb, dec_emb, enc_x, dec_e);
    hipLaunchKernelGGL(init_kernel, dim3(16), dim3(256), 0, stream, hbuf, bar_all);

    // phase 1: batched pre-GEMMs
    hipLaunchKernelGGL(gemm_nt_kernel, dim3(3 * H / 64, SEQ / 64), dim3(256), 0, stream,
                       enc_x, enc_Wi, enc_bi, enc_gi, H, H, 0, H, 3 * H);
    hipLaunchKernelGGL(gemm_nt_kernel, dim3(SEQ / 64, SEQ / 64), dim3(256), 0, stream,
                       dec_e, attn_W, attn_b, attn_e, H, H, 0, 2 * H, SEQ);
    hipLaunchKernelGGL(gemm_nt_kernel, dim3(H / 64, SEQ / 64), dim3(256), 0, stream,
                       dec_e, comb_W, comb_b, comb_pre, H, H, 0, 2 * H, H);

    // phase 2: encoder recurrence (cooperative launch for residency guarantee)
    {
        void* args[] = {(void*)&enc_Wh, (void*)&enc_bh, (void*)&enc_gi,
                        (void*)&hbuf, (void*)&encH, (void*)&bar_enc};
        hipLaunchCooperativeKernel((void*)enc_rnn_kernel, dim3(256), dim3(256),
                                   args, 0, stream);
    }

    // phase 2.5: M = comb_W[:,H:] @ encH^T
    hipLaunchKernelGGL(gemm_nt_kernel, dim3(SEQ / 64, H / 64), dim3(256), 0, stream,
                       comb_W, encH, (const float*)nullptr, Mmat, H, 2 * H, H, H, SEQ);

    // phase 3: decoder recurrence
    {
        void* args[] = {(void*)&attn_W, (void*)&attn_e, (void*)&Mmat, (void*)&comb_pre,
                        (void*)&dec_Wi, (void*)&dec_Wh, (void*)&dec_bi, (void*)&dec_bh,
                        (void*)&hbuf, (void*)&s_g, (void*)&c_g, (void*)&hs_dec,
                        (void*)&bar_dec};
        hipLaunchCooperativeKernel((void*)dec_rnn_kernel, dim3(256), dim3(256),
                                   args, 0, stream);
    }

    // phase 4: logits = hs_dec @ out_W^T + out_b
    hipLaunchKernelGGL(gemm_nt_kernel, dim3(VOUT / 64, SEQ / 64), dim3(256), 0, stream,
                       hs_dec, out_W, out_b, logits, H, H, 0, H, VOUT);

    // phase 5: NLL + total
    hipLaunchKernelGGL(nll_kernel, dim3(SEQ), dim3(256), 0, stream,
                       logits, target_ids, nll);
    hipLaunchKernelGGL(sum_kernel, dim3(1), dim3(256), 0, stream, nll, out);
}